// Round 11
// baseline (400.682 us; speedup 1.0000x reference)
//
#include <hip/hip_runtime.h>
#include <hip/hip_fp16.h>

#define N_NODES 100000
#define N_EDGES 1600000
#define NPB 128                                   // nodes per dst-bucket
#define NBK ((N_NODES + NPB - 1) / NPB)           // 782 buckets
#define FBLK 128                                  // fill blocks
#define EPB ((N_EDGES + FBLK - 1) / FBLK)         // 12500 edges per fill block
#define CAP 4096                                  // LDS capacity per bucket (mean 2046, sigma ~45)

// ---------------- pass 1: per-block bucket histograms (validated r9/r10) ----------------

__global__ void __launch_bounds__(256) hist_kernel(const int* __restrict__ dst, int* __restrict__ H) {
    __shared__ int h[NBK];
    for (int i = threadIdx.x; i < NBK; i += 256) h[i] = 0;
    __syncthreads();
    const int e0 = blockIdx.x * EPB;
    const int e1 = min(e0 + EPB, N_EDGES);
    for (int e = e0 + threadIdx.x; e < e1; e += 256) atomicAdd(&h[dst[e] >> 7], 1);
    __syncthreads();
    for (int i = threadIdx.x; i < NBK; i += 256) H[blockIdx.x * NBK + i] = h[i];
}

// ---------------- pass 2a: per-bucket column scan over the 128 blocks ----------------

__global__ void __launch_bounds__(256) colscan_kernel(int* __restrict__ H, int* __restrict__ btot) {
    const int t = blockIdx.x * 256 + threadIdx.x;
    if (t >= NBK) return;
    int run = 0;
    for (int k = 0; k < FBLK; ++k) {
        int idx = k * NBK + t;
        int h = H[idx];
        H[idx] = run;
        run += h;
    }
    btot[t] = run;
}

// ---------------- pass 2b: scan bucket totals -> bucket bases + bptr ----------------

__global__ void __launch_bounds__(1024) bucketscan_kernel(const int* __restrict__ btot,
                                                          int* __restrict__ bbase, int* __restrict__ bptr) {
    __shared__ int sh[1024];
    const int t = threadIdx.x;
    int v = (t < NBK) ? btot[t] : 0;
    sh[t] = v;
    __syncthreads();
    for (int off = 1; off < 1024; off <<= 1) {
        int u = (t >= off) ? sh[t - off] : 0;
        __syncthreads();
        sh[t] += u;
        __syncthreads();
    }
    if (t < NBK) { int e = sh[t] - v; bbase[t] = e; bptr[t] = e; }
    if (t == 0) bptr[NBK] = N_EDGES;
}

// ---------------- pass 3: bin edges by bucket (LDS cursors) ----------------

__global__ void __launch_bounds__(256) binfill_kernel(const int* __restrict__ src, const int* __restrict__ dst,
                                                      const int* __restrict__ H, const int* __restrict__ bbase,
                                                      int* __restrict__ tmp) {
    __shared__ int cur[NBK];
    const int k = blockIdx.x;
    for (int i = threadIdx.x; i < NBK; i += 256) cur[i] = H[k * NBK + i] + bbase[i];
    __syncthreads();
    const int e0 = k * EPB;
    const int e1 = min(e0 + EPB, N_EDGES);
    for (int e = e0 + threadIdx.x; e < e1; e += 256) {
        int s = src[e];
        int d = dst[e];
        int pos = atomicAdd(&cur[d >> 7], 1);
        tmp[pos] = s | ((d & (NPB - 1)) << 20);
    }
}

// ---------------- pass 4: per-bucket count/scan/rowptr/dis + LDS sort -> esrc ----------------

__global__ void __launch_bounds__(256) bucketfin_kernel(const int* __restrict__ tmp, const int* __restrict__ bptr,
                                                        int* __restrict__ esrc, int* __restrict__ rowptr,
                                                        float* __restrict__ dis, int n) {
    __shared__ int buf[CAP];
    __shared__ int cnt[NPB];
    __shared__ int sc[NPB];
    __shared__ int rp[NPB];
    __shared__ int fillc[NPB];
    const int b = blockIdx.x;
    const int d0 = b * NPB;
    const int nd = min(NPB, n - d0);
    const int base = bptr[b], end = bptr[b + 1];
    const int count = end - base;
    const int tid = threadIdx.x;

    for (int i = tid; i < NPB; i += 256) { cnt[i] = 0; fillc[i] = 0; }
    __syncthreads();
    for (int e = base + tid; e < end; e += 256) atomicAdd(&cnt[tmp[e] >> 20], 1);
    __syncthreads();

    if (tid < NPB) sc[tid] = cnt[tid];
    __syncthreads();
    for (int off = 1; off < NPB; off <<= 1) {
        int v = (tid < NPB && tid >= off) ? sc[tid - off] : 0;
        __syncthreads();
        if (tid < NPB) sc[tid] += v;
        __syncthreads();
    }
    if (tid < NPB) {
        int excl = sc[tid] - cnt[tid];
        rp[tid] = excl;
        if (tid < nd) {
            rowptr[d0 + tid] = base + excl;
            dis[d0 + tid] = rsqrtf((float)cnt[tid] + 1.0f);
        }
    }
    if (b == NBK - 1 && tid == 0) rowptr[n] = N_EDGES;
    __syncthreads();

    if (count <= CAP) {
        for (int t = base + tid; t < end; t += 256) {
            int w = tmp[t];
            int ld = w >> 20;
            int pos = rp[ld] + atomicAdd(&fillc[ld], 1);
            buf[pos] = w & 0xFFFFF;
        }
        __syncthreads();
        for (int t = tid; t < count; t += 256) esrc[base + t] = buf[t];
    } else {
        for (int t = base + tid; t < end; t += 256) {
            int w = tmp[t];
            int ld = w >> 20;
            int pos = rp[ld] + atomicAdd(&fillc[ld], 1);
            esrc[base + pos] = w & 0xFFFFF;
        }
    }
}

// ---------------- all 3 weight transposes in one launch ----------------

__global__ void transpose_all_kernel(const float* __restrict__ W0, const float* __restrict__ W1,
                                     const float* __restrict__ W2, float* __restrict__ wt0,
                                     float* __restrict__ wt1, float* __restrict__ wt2) {
    int i = blockIdx.x * blockDim.x + threadIdx.x;
    if (i < 8192)       { int k = i / 64, c = i % 64;                 wt0[c * 128 + k] = W0[i]; }
    else if (i < 12288) { int j = i - 8192;  int k = j / 64, c = j % 64; wt1[c * 64 + k] = W1[j]; }
    else if (i < 14336) { int j = i - 12288; int k = j / 32, c = j % 32; wt2[c * 64 + k] = W2[j]; }
}

// ---------------- dense GEMM: W in LDS (staged once), X read direct from global ----------------
// ys[row] = fp16(dis[row] * (x[row] @ W)); 4 rows x 4 cols per thread.
// x loads: 16 lanes share each address -> coalesced broadcast; no per-K-tile sync.

template <int DIN, int DOUT>
__global__ void __launch_bounds__(256) gemm_kernel(const float* __restrict__ x,
                                                   const float* __restrict__ Wt,
                                                   const float* __restrict__ dis,
                                                   __half* __restrict__ ys, int n) {
    constexpr int TPC  = DOUT / 4;            // threads covering col dim (4 cols each)
    constexpr int ROWS = (256 / TPC) * 4;     // rows per block (64 or 128)
    constexpr int WS   = DIN + 4;             // padded stride, 16B-aligned

    __shared__ float Wl[DOUT * WS];

    for (int i = 4 * threadIdx.x; i < DIN * DOUT; i += 1024) {
        int c = i / DIN, k = i % DIN;
        float4 v = *(const float4*)&Wt[i];
        *(float4*)&Wl[c * WS + k] = v;
    }
    __syncthreads();

    const int row0 = blockIdx.x * ROWS;
    const int g    = threadIdx.x / TPC;
    const int c0   = threadIdx.x % TPC;
    const int r0   = row0 + g * 4;
    if (r0 >= n) return;

    const float* w0 = &Wl[(c0 + 0 * TPC) * WS];
    const float* w1 = &Wl[(c0 + 1 * TPC) * WS];
    const float* w2 = &Wl[(c0 + 2 * TPC) * WS];
    const float* w3 = &Wl[(c0 + 3 * TPC) * WS];

    float4 acc[4];
#pragma unroll
    for (int r = 0; r < 4; ++r) acc[r] = make_float4(0.f, 0.f, 0.f, 0.f);

    if (r0 + 3 < n) {
        const float* xr0 = &x[(long)(r0 + 0) * DIN];
        const float* xr1 = &x[(long)(r0 + 1) * DIN];
        const float* xr2 = &x[(long)(r0 + 2) * DIN];
        const float* xr3 = &x[(long)(r0 + 3) * DIN];
#pragma unroll 4
        for (int k = 0; k < DIN; k += 4) {
            float4 a = *(const float4*)&w0[k];
            float4 b = *(const float4*)&w1[k];
            float4 c = *(const float4*)&w2[k];
            float4 d = *(const float4*)&w3[k];
            float4 x0 = *(const float4*)&xr0[k];
            float4 x1 = *(const float4*)&xr1[k];
            float4 x2 = *(const float4*)&xr2[k];
            float4 x3 = *(const float4*)&xr3[k];
            acc[0].x += x0.x * a.x + x0.y * a.y + x0.z * a.z + x0.w * a.w;
            acc[0].y += x0.x * b.x + x0.y * b.y + x0.z * b.z + x0.w * b.w;
            acc[0].z += x0.x * c.x + x0.y * c.y + x0.z * c.z + x0.w * c.w;
            acc[0].w += x0.x * d.x + x0.y * d.y + x0.z * d.z + x0.w * d.w;
            acc[1].x += x1.x * a.x + x1.y * a.y + x1.z * a.z + x1.w * a.w;
            acc[1].y += x1.x * b.x + x1.y * b.y + x1.z * b.z + x1.w * b.w;
            acc[1].z += x1.x * c.x + x1.y * c.y + x1.z * c.z + x1.w * c.w;
            acc[1].w += x1.x * d.x + x1.y * d.y + x1.z * d.z + x1.w * d.w;
            acc[2].x += x2.x * a.x + x2.y * a.y + x2.z * a.z + x2.w * a.w;
            acc[2].y += x2.x * b.x + x2.y * b.y + x2.z * b.z + x2.w * b.w;
            acc[2].z += x2.x * c.x + x2.y * c.y + x2.z * c.z + x2.w * c.w;
            acc[2].w += x2.x * d.x + x2.y * d.y + x2.z * d.z + x2.w * d.w;
            acc[3].x += x3.x * a.x + x3.y * a.y + x3.z * a.z + x3.w * a.w;
            acc[3].y += x3.x * b.x + x3.y * b.y + x3.z * b.z + x3.w * b.w;
            acc[3].z += x3.x * c.x + x3.y * c.y + x3.z * c.z + x3.w * c.w;
            acc[3].w += x3.x * d.x + x3.y * d.y + x3.z * d.z + x3.w * d.w;
        }
    } else {
        for (int r = 0; r < 4; ++r) {
            const int row = r0 + r;
            if (row >= n) break;
            const float* xr = &x[(long)row * DIN];
            float4 ar = make_float4(0.f, 0.f, 0.f, 0.f);
            for (int k = 0; k < DIN; k += 4) {
                float4 a = *(const float4*)&w0[k];
                float4 b = *(const float4*)&w1[k];
                float4 c = *(const float4*)&w2[k];
                float4 d = *(const float4*)&w3[k];
                float4 xv = *(const float4*)&xr[k];
                ar.x += xv.x * a.x + xv.y * a.y + xv.z * a.z + xv.w * a.w;
                ar.y += xv.x * b.x + xv.y * b.y + xv.z * b.z + xv.w * b.w;
                ar.z += xv.x * c.x + xv.y * c.y + xv.z * c.z + xv.w * c.w;
                ar.w += xv.x * d.x + xv.y * d.y + xv.z * d.z + xv.w * d.w;
            }
            acc[r] = ar;
        }
    }

#pragma unroll
    for (int r = 0; r < 4; ++r) {
        const int row = r0 + r;
        if (row < n) {
            const float ds = dis[row];
            __half* yr = &ys[(long)row * DOUT];
            yr[c0 + 0 * TPC] = __float2half(acc[r].x * ds);
            yr[c0 + 1 * TPC] = __float2half(acc[r].y * ds);
            yr[c0 + 2 * TPC] = __float2half(acc[r].z * ds);
            yr[c0 + 3 * TPC] = __float2half(acc[r].w * ds);
        }
    }
}

// ---------------- gather DOUT=64: 1 node/wave, 2 edge-parity groups, unroll 4 ----------------
// out[d] = dis[d] * (ys[d] + sum_edges ys[s]) + b   (dis_s folded into ys at GEMM)

template <bool RELU>
__global__ void gather2h_kernel(const int* __restrict__ rowptr, const int* __restrict__ esrc,
                                const __half* __restrict__ ys, const float* __restrict__ dis,
                                const float* __restrict__ b, float* __restrict__ out, int n) {
    const int node = blockIdx.x * 4 + (threadIdx.x >> 6);
    const int lane = threadIdx.x & 63;
    const int par  = lane >> 5;          // 0/1: edge parity
    const int c    = (lane & 31) * 2;
    if (node >= n) return;

    float ax = 0.f, ay = 0.f;
    const int end = rowptr[node + 1];
    int k = rowptr[node] + par;
    for (; k + 6 < end; k += 8) {
        int u0 = esrc[k], u1 = esrc[k + 2], u2 = esrc[k + 4], u3 = esrc[k + 6];
        float2 v0 = __half22float2(*(const __half2*)&ys[(long)u0 * 64 + c]);
        float2 v1 = __half22float2(*(const __half2*)&ys[(long)u1 * 64 + c]);
        float2 v2 = __half22float2(*(const __half2*)&ys[(long)u2 * 64 + c]);
        float2 v3 = __half22float2(*(const __half2*)&ys[(long)u3 * 64 + c]);
        ax += v0.x; ay += v0.y;
        ax += v1.x; ay += v1.y;
        ax += v2.x; ay += v2.y;
        ax += v3.x; ay += v3.y;
    }
    for (; k < end; k += 2) {
        int u = esrc[k];
        float2 v = __half22float2(*(const __half2*)&ys[(long)u * 64 + c]);
        ax += v.x; ay += v.y;
    }

    ax += __shfl_down(ax, 32);
    ay += __shfl_down(ay, 32);

    if (par == 0) {
        float2 yv = __half22float2(*(const __half2*)&ys[(long)node * 64 + c]);
        const float di = dis[node];
        float rx = (yv.x + ax) * di + b[c];
        float ry = (yv.y + ay) * di + b[c + 1];
        if (RELU) { rx = fmaxf(rx, 0.0f); ry = fmaxf(ry, 0.0f); }
        *(float2*)&out[(long)node * 64 + c] = make_float2(rx, ry);
    }
}

// ---------------- gather DOUT=32: 1 node/wave, 4 edge-parity groups, unroll 2 ----------------

template <bool RELU>
__global__ void gather4h_kernel(const int* __restrict__ rowptr, const int* __restrict__ esrc,
                                const __half* __restrict__ ys, const float* __restrict__ dis,
                                const float* __restrict__ b, float* __restrict__ out, int n) {
    const int node = blockIdx.x * 4 + (threadIdx.x >> 6);
    const int lane = threadIdx.x & 63;
    const int par  = lane >> 4;          // 0..3: edge parity
    const int c    = (lane & 15) * 2;
    if (node >= n) return;

    float ax = 0.f, ay = 0.f;
    const int end = rowptr[node + 1];
    int k = rowptr[node] + par;
    for (; k + 4 < end; k += 8) {
        int u0 = esrc[k], u1 = esrc[k + 4];
        float2 v0 = __half22float2(*(const __half2*)&ys[(long)u0 * 32 + c]);
        float2 v1 = __half22float2(*(const __half2*)&ys[(long)u1 * 32 + c]);
        ax += v0.x; ay += v0.y;
        ax += v1.x; ay += v1.y;
    }
    for (; k < end; k += 4) {
        int u = esrc[k];
        float2 v = __half22float2(*(const __half2*)&ys[(long)u * 32 + c]);
        ax += v.x; ay += v.y;
    }

    ax += __shfl_down(ax, 32);
    ay += __shfl_down(ay, 32);
    ax += __shfl_down(ax, 16);
    ay += __shfl_down(ay, 16);

    if (par == 0) {
        float2 yv = __half22float2(*(const __half2*)&ys[(long)node * 32 + c]);
        const float di = dis[node];
        float rx = (yv.x + ax) * di + b[c];
        float ry = (yv.y + ay) * di + b[c + 1];
        if (RELU) { rx = fmaxf(rx, 0.0f); ry = fmaxf(ry, 0.0f); }
        *(float2*)&out[(long)node * 32 + c] = make_float2(rx, ry);
    }
}

// ---------------- launch ----------------

extern "C" void kernel_launch(void* const* d_in, const int* in_sizes, int n_in,
                              void* d_out, int out_size, void* d_ws, size_t ws_size,
                              hipStream_t stream) {
    const float* features = (const float*)d_in[0];
    const int*   ei       = (const int*)d_in[1];
    const float* W0 = (const float*)d_in[2];
    const float* b0 = (const float*)d_in[3];
    const float* W1 = (const float*)d_in[4];
    const float* b1 = (const float*)d_in[5];
    const float* W2 = (const float*)d_in[6];
    const float* b2 = (const float*)d_in[7];

    const int* src = ei;             // edge_index[0]
    const int* dst = ei + N_EDGES;   // edge_index[1]

    const int n = N_NODES;

    // workspace layout (int slots) — r10 layout
    int*    H      = (int*)d_ws;                       // [0, 131072)
    int*    btot   = (int*)d_ws + 131072;              // [131072, 132096)
    int*    bbase  = (int*)d_ws + 132096;              // [132096, 133120)
    int*    bptr   = (int*)d_ws + 133120;              // [133120, 135168)
    float*  dis    = (float*)d_ws + 135168;            // [135168, 266240)
    int*    rowptr = (int*)d_ws + 266240;              // [266240, 397312)  n+1 fits
    int*    tmp    = (int*)d_ws + 397312;              // E ints
    int*    esrc   = (int*)d_ws + 1997312;             // E ints
    __half* ys     = (__half*)((int*)d_ws + 3597312);  // N*64 halves
    float*  act    = (float*)d_ws + 6797312;           // N*64 floats
    float*  wt0    = (float*)d_ws + 13197312;          // 8192
    float*  wt1    = wt0 + 8192;                       // 4096
    float*  wt2    = wt1 + 4096;                       // 2048
    float*  outf   = (float*)d_out;                    // N*32 fp32

    // ---- contention-free CSR build + transposes ----
    hist_kernel<<<FBLK, 256, 0, stream>>>(dst, H);
    colscan_kernel<<<(NBK + 255) / 256, 256, 0, stream>>>(H, btot);
    bucketscan_kernel<<<1, 1024, 0, stream>>>(btot, bbase, bptr);
    binfill_kernel<<<FBLK, 256, 0, stream>>>(src, dst, H, bbase, tmp);
    bucketfin_kernel<<<NBK, 256, 0, stream>>>(tmp, bptr, esrc, rowptr, dis, n);
    transpose_all_kernel<<<56, 256, 0, stream>>>(W0, W1, W2, wt0, wt1, wt2);

    // ---- layer 0: 128 -> 64, ReLU ----
    gemm_kernel<128, 64><<<(n + 63) / 64, 256, 0, stream>>>(features, wt0, dis, ys, n);
    gather2h_kernel<true><<<(n + 3) / 4, 256, 0, stream>>>(rowptr, esrc, ys, dis, b0, act, n);

    // ---- layer 1: 64 -> 64, ReLU ----
    gemm_kernel<64, 64><<<(n + 63) / 64, 256, 0, stream>>>(act, wt1, dis, ys, n);
    gather2h_kernel<true><<<(n + 3) / 4, 256, 0, stream>>>(rowptr, esrc, ys, dis, b1, act, n);

    // ---- layer 2: 64 -> 32, no ReLU ----
    gemm_kernel<64, 32><<<(n + 127) / 128, 256, 0, stream>>>(act, wt2, dis, ys, n);
    gather4h_kernel<false><<<(n + 3) / 4, 256, 0, stream>>>(rowptr, esrc, ys, dis, b2, outf, n);
}

// Round 12
// 338.523 us; speedup vs baseline: 1.1836x; 1.1836x over previous
//
#include <hip/hip_runtime.h>
#include <hip/hip_fp16.h>

#define N_NODES 100000
#define N_EDGES 1600000
#define NPB 128                                   // nodes per dst-bucket
#define NBK ((N_NODES + NPB - 1) / NPB)           // 782 buckets
#define FBLK 128                                  // fill blocks
#define EPB ((N_EDGES + FBLK - 1) / FBLK)         // 12500 edges per fill block
#define CAP 4096                                  // LDS capacity per bucket (mean 2046, sigma ~45)

typedef _Float16 h8 __attribute__((ext_vector_type(8)));
typedef float f4v __attribute__((ext_vector_type(4)));

// ---------------- pass 1: per-block bucket histograms (validated r9/r10) ----------------

__global__ void __launch_bounds__(256) hist_kernel(const int* __restrict__ dst, int* __restrict__ H) {
    __shared__ int h[NBK];
    for (int i = threadIdx.x; i < NBK; i += 256) h[i] = 0;
    __syncthreads();
    const int e0 = blockIdx.x * EPB;
    const int e1 = min(e0 + EPB, N_EDGES);
    for (int e = e0 + threadIdx.x; e < e1; e += 256) atomicAdd(&h[dst[e] >> 7], 1);
    __syncthreads();
    for (int i = threadIdx.x; i < NBK; i += 256) H[blockIdx.x * NBK + i] = h[i];
}

// ---------------- pass 2a: per-bucket column scan over the 128 blocks ----------------

__global__ void __launch_bounds__(256) colscan_kernel(int* __restrict__ H, int* __restrict__ btot) {
    const int t = blockIdx.x * 256 + threadIdx.x;
    if (t >= NBK) return;
    int run = 0;
    for (int k = 0; k < FBLK; ++k) {
        int idx = k * NBK + t;
        int h = H[idx];
        H[idx] = run;
        run += h;
    }
    btot[t] = run;
}

// ---------------- pass 2b: scan bucket totals -> bucket bases + bptr ----------------

__global__ void __launch_bounds__(1024) bucketscan_kernel(const int* __restrict__ btot,
                                                          int* __restrict__ bbase, int* __restrict__ bptr) {
    __shared__ int sh[1024];
    const int t = threadIdx.x;
    int v = (t < NBK) ? btot[t] : 0;
    sh[t] = v;
    __syncthreads();
    for (int off = 1; off < 1024; off <<= 1) {
        int u = (t >= off) ? sh[t - off] : 0;
        __syncthreads();
        sh[t] += u;
        __syncthreads();
    }
    if (t < NBK) { int e = sh[t] - v; bbase[t] = e; bptr[t] = e; }
    if (t == 0) bptr[NBK] = N_EDGES;
}

// ---------------- pass 3: bin edges by bucket (LDS cursors) ----------------

__global__ void __launch_bounds__(256) binfill_kernel(const int* __restrict__ src, const int* __restrict__ dst,
                                                      const int* __restrict__ H, const int* __restrict__ bbase,
                                                      int* __restrict__ tmp) {
    __shared__ int cur[NBK];
    const int k = blockIdx.x;
    for (int i = threadIdx.x; i < NBK; i += 256) cur[i] = H[k * NBK + i] + bbase[i];
    __syncthreads();
    const int e0 = k * EPB;
    const int e1 = min(e0 + EPB, N_EDGES);
    for (int e = e0 + threadIdx.x; e < e1; e += 256) {
        int s = src[e];
        int d = dst[e];
        int pos = atomicAdd(&cur[d >> 7], 1);
        tmp[pos] = s | ((d & (NPB - 1)) << 20);
    }
}

// ---------------- pass 4: per-bucket count/scan/rowptr/dis + LDS sort -> esrc ----------------

__global__ void __launch_bounds__(256) bucketfin_kernel(const int* __restrict__ tmp, const int* __restrict__ bptr,
                                                        int* __restrict__ esrc, int* __restrict__ rowptr,
                                                        float* __restrict__ dis, int n) {
    __shared__ int buf[CAP];
    __shared__ int cnt[NPB];
    __shared__ int sc[NPB];
    __shared__ int rp[NPB];
    __shared__ int fillc[NPB];
    const int b = blockIdx.x;
    const int d0 = b * NPB;
    const int nd = min(NPB, n - d0);
    const int base = bptr[b], end = bptr[b + 1];
    const int count = end - base;
    const int tid = threadIdx.x;

    for (int i = tid; i < NPB; i += 256) { cnt[i] = 0; fillc[i] = 0; }
    __syncthreads();
    for (int e = base + tid; e < end; e += 256) atomicAdd(&cnt[tmp[e] >> 20], 1);
    __syncthreads();

    if (tid < NPB) sc[tid] = cnt[tid];
    __syncthreads();
    for (int off = 1; off < NPB; off <<= 1) {
        int v = (tid < NPB && tid >= off) ? sc[tid - off] : 0;
        __syncthreads();
        if (tid < NPB) sc[tid] += v;
        __syncthreads();
    }
    if (tid < NPB) {
        int excl = sc[tid] - cnt[tid];
        rp[tid] = excl;
        if (tid < nd) {
            rowptr[d0 + tid] = base + excl;
            dis[d0 + tid] = rsqrtf((float)cnt[tid] + 1.0f);
        }
    }
    if (b == NBK - 1 && tid == 0) rowptr[n] = N_EDGES;
    __syncthreads();

    if (count <= CAP) {
        for (int t = base + tid; t < end; t += 256) {
            int w = tmp[t];
            int ld = w >> 20;
            int pos = rp[ld] + atomicAdd(&fillc[ld], 1);
            buf[pos] = w & 0xFFFFF;
        }
        __syncthreads();
        for (int t = tid; t < count; t += 256) esrc[base + t] = buf[t];
    } else {
        for (int t = base + tid; t < end; t += 256) {
            int w = tmp[t];
            int ld = w >> 20;
            int pos = rp[ld] + atomicAdd(&fillc[ld], 1);
            esrc[base + pos] = w & 0xFFFFF;
        }
    }
}

// ---------------- weight transposes -> fp16 W^T ----------------

__global__ void transpose_all_kernel(const float* __restrict__ W0, const float* __restrict__ W1,
                                     const float* __restrict__ W2, __half* __restrict__ wt0,
                                     __half* __restrict__ wt1, __half* __restrict__ wt2) {
    int i = blockIdx.x * blockDim.x + threadIdx.x;
    if (i < 8192)       { int k = i / 64, c = i % 64;                 wt0[c * 128 + k] = __float2half(W0[i]); }
    else if (i < 12288) { int j = i - 8192;  int k = j / 64, c = j % 64; wt1[c * 64 + k] = __float2half(W1[j]); }
    else if (i < 14336) { int j = i - 12288; int k = j / 32, c = j % 32; wt2[c * 64 + k] = __float2half(W2[j]); }
}

// ---------------- MFMA GEMM: ys[n,DOUT] = fp16(dis[row] * (x[n,DIN] @ W)) ----------------
// 64 rows/block, 4 waves; wave w owns rows w*16..w*16+15, all DOUT cols (NT=DOUT/16 acc frags).
// A-frag: A[m=lane&15][k=quad*8+j]  (x staged fp32->fp16 in LDS, stride DIN+8)
// B-frag: B[k=quad*8+j][n=lane&15]  (wt16 = W^T fp16, row n contiguous in k)
// C/D:    col=lane&15, row=quad*4+reg    [verified layouts, m89/m120]

template <int DIN, int DOUT>
__global__ void __launch_bounds__(256) gemm_kernel(const float* __restrict__ x,
                                                   const __half* __restrict__ wt16,
                                                   const float* __restrict__ dis,
                                                   __half* __restrict__ ys, int n) {
    constexpr int WS = DIN + 8;          // half-element stride (16B-aligned, 2-way banks = free)
    constexpr int NT = DOUT / 16;
    constexpr int KC = DIN / 32;

    __shared__ _Float16 xls[64 * WS];
    __shared__ _Float16 wls[DOUT * WS];

    const int tid  = threadIdx.x;
    const int row0 = blockIdx.x * 64;

    // stage W (fp16, 16B chunks)
    for (int i = tid; i < DOUT * DIN / 8; i += 256) {
        int c = (i * 8) / DIN, k = (i * 8) % DIN;
        *(int4*)&wls[c * WS + k] = *(const int4*)&wt16[c * DIN + k];
    }
    // stage x (fp32 -> fp16)
    for (int i = tid; i < 64 * DIN / 4; i += 256) {
        int r = (i * 4) / DIN, k = (i * 4) % DIN;
        float4 v = make_float4(0.f, 0.f, 0.f, 0.f);
        if (row0 + r < n) v = *(const float4*)&x[(long)(row0 + r) * DIN + k];
        _Float16 h[4] = {(_Float16)v.x, (_Float16)v.y, (_Float16)v.z, (_Float16)v.w};
        *(int2*)&xls[r * WS + k] = *(int2*)h;
    }
    __syncthreads();

    const int wave = tid >> 6;
    const int lane = tid & 63;
    const int m16  = lane & 15;
    const int quad = lane >> 4;

    f4v acc[NT];
#pragma unroll
    for (int t = 0; t < NT; ++t) acc[t] = (f4v){0.f, 0.f, 0.f, 0.f};

    const int arow = wave * 16 + m16;
#pragma unroll
    for (int kc = 0; kc < KC; ++kc) {
        h8 a = *(const h8*)&xls[arow * WS + kc * 32 + quad * 8];
#pragma unroll
        for (int t = 0; t < NT; ++t) {
            h8 b = *(const h8*)&wls[(t * 16 + m16) * WS + kc * 32 + quad * 8];
            acc[t] = __builtin_amdgcn_mfma_f32_16x16x32_f16(a, b, acc[t], 0, 0, 0);
        }
    }

    // epilogue: row = row0 + wave*16 + quad*4 + reg, col = t*16 + m16
    float dsv[4];
    int   rows[4];
#pragma unroll
    for (int reg = 0; reg < 4; ++reg) {
        rows[reg] = row0 + wave * 16 + quad * 4 + reg;
        dsv[reg]  = (rows[reg] < n) ? dis[rows[reg]] : 0.f;
    }
#pragma unroll
    for (int t = 0; t < NT; ++t) {
#pragma unroll
        for (int reg = 0; reg < 4; ++reg) {
            if (rows[reg] < n)
                ys[(long)rows[reg] * DOUT + t * 16 + m16] = __float2half(acc[t][reg] * dsv[reg]);
        }
    }
}

// ---------------- gather DOUT=64: 1 node/wave, 2 edge-parity groups (validated r11) ----------------
// out[d] = dis[d] * (ys[d] + sum_edges ys[s]) + b   (dis_s folded into ys at GEMM)

template <bool RELU>
__global__ void gather2h_kernel(const int* __restrict__ rowptr, const int* __restrict__ esrc,
                                const __half* __restrict__ ys, const float* __restrict__ dis,
                                const float* __restrict__ b, float* __restrict__ out, int n) {
    const int node = blockIdx.x * 4 + (threadIdx.x >> 6);
    const int lane = threadIdx.x & 63;
    const int par  = lane >> 5;          // 0/1: edge parity
    const int c    = (lane & 31) * 2;
    if (node >= n) return;

    float ax = 0.f, ay = 0.f;
    const int end = rowptr[node + 1];
    int k = rowptr[node] + par;
    for (; k + 6 < end; k += 8) {
        int u0 = esrc[k], u1 = esrc[k + 2], u2 = esrc[k + 4], u3 = esrc[k + 6];
        float2 v0 = __half22float2(*(const __half2*)&ys[(long)u0 * 64 + c]);
        float2 v1 = __half22float2(*(const __half2*)&ys[(long)u1 * 64 + c]);
        float2 v2 = __half22float2(*(const __half2*)&ys[(long)u2 * 64 + c]);
        float2 v3 = __half22float2(*(const __half2*)&ys[(long)u3 * 64 + c]);
        ax += v0.x; ay += v0.y;
        ax += v1.x; ay += v1.y;
        ax += v2.x; ay += v2.y;
        ax += v3.x; ay += v3.y;
    }
    for (; k < end; k += 2) {
        int u = esrc[k];
        float2 v = __half22float2(*(const __half2*)&ys[(long)u * 64 + c]);
        ax += v.x; ay += v.y;
    }

    ax += __shfl_down(ax, 32);
    ay += __shfl_down(ay, 32);

    if (par == 0) {
        float2 yv = __half22float2(*(const __half2*)&ys[(long)node * 64 + c]);
        const float di = dis[node];
        float rx = (yv.x + ax) * di + b[c];
        float ry = (yv.y + ay) * di + b[c + 1];
        if (RELU) { rx = fmaxf(rx, 0.0f); ry = fmaxf(ry, 0.0f); }
        *(float2*)&out[(long)node * 64 + c] = make_float2(rx, ry);
    }
}

// ---------------- gather DOUT=32: 1 node/wave, 4 edge-parity groups (validated r11) ----------------

template <bool RELU>
__global__ void gather4h_kernel(const int* __restrict__ rowptr, const int* __restrict__ esrc,
                                const __half* __restrict__ ys, const float* __restrict__ dis,
                                const float* __restrict__ b, float* __restrict__ out, int n) {
    const int node = blockIdx.x * 4 + (threadIdx.x >> 6);
    const int lane = threadIdx.x & 63;
    const int par  = lane >> 4;          // 0..3: edge parity
    const int c    = (lane & 15) * 2;
    if (node >= n) return;

    float ax = 0.f, ay = 0.f;
    const int end = rowptr[node + 1];
    int k = rowptr[node] + par;
    for (; k + 4 < end; k += 8) {
        int u0 = esrc[k], u1 = esrc[k + 4];
        float2 v0 = __half22float2(*(const __half2*)&ys[(long)u0 * 32 + c]);
        float2 v1 = __half22float2(*(const __half2*)&ys[(long)u1 * 32 + c]);
        ax += v0.x; ay += v0.y;
        ax += v1.x; ay += v1.y;
    }
    for (; k < end; k += 4) {
        int u = esrc[k];
        float2 v = __half22float2(*(const __half2*)&ys[(long)u * 32 + c]);
        ax += v.x; ay += v.y;
    }

    ax += __shfl_down(ax, 32);
    ay += __shfl_down(ay, 32);
    ax += __shfl_down(ax, 16);
    ay += __shfl_down(ay, 16);

    if (par == 0) {
        float2 yv = __half22float2(*(const __half2*)&ys[(long)node * 32 + c]);
        const float di = dis[node];
        float rx = (yv.x + ax) * di + b[c];
        float ry = (yv.y + ay) * di + b[c + 1];
        if (RELU) { rx = fmaxf(rx, 0.0f); ry = fmaxf(ry, 0.0f); }
        *(float2*)&out[(long)node * 32 + c] = make_float2(rx, ry);
    }
}

// ---------------- launch ----------------

extern "C" void kernel_launch(void* const* d_in, const int* in_sizes, int n_in,
                              void* d_out, int out_size, void* d_ws, size_t ws_size,
                              hipStream_t stream) {
    const float* features = (const float*)d_in[0];
    const int*   ei       = (const int*)d_in[1];
    const float* W0 = (const float*)d_in[2];
    const float* b0 = (const float*)d_in[3];
    const float* W1 = (const float*)d_in[4];
    const float* b1 = (const float*)d_in[5];
    const float* W2 = (const float*)d_in[6];
    const float* b2 = (const float*)d_in[7];

    const int* src = ei;             // edge_index[0]
    const int* dst = ei + N_EDGES;   // edge_index[1]

    const int n = N_NODES;

    // workspace layout (int slots)
    int*    H      = (int*)d_ws;                       // [0, 131072)
    int*    btot   = (int*)d_ws + 131072;              // [131072, 132096)
    int*    bbase  = (int*)d_ws + 132096;              // [132096, 133120)
    int*    bptr   = (int*)d_ws + 133120;              // [133120, 135168)
    float*  dis    = (float*)d_ws + 135168;            // [135168, 266240)
    int*    rowptr = (int*)d_ws + 266240;              // [266240, 397312)  n+1 fits
    int*    tmp    = (int*)d_ws + 397312;              // E ints
    int*    esrc   = (int*)d_ws + 1997312;             // E ints
    __half* ys     = (__half*)((int*)d_ws + 3597312);  // N*64 halves
    float*  act    = (float*)d_ws + 6797312;           // N*64 floats
    __half* wt0    = (__half*)((int*)d_ws + 13197312); // 8192 halves = 4096 ints
    __half* wt1    = (__half*)((int*)d_ws + 13201408); // 4096 halves = 2048 ints
    __half* wt2    = (__half*)((int*)d_ws + 13203456); // 2048 halves = 1024 ints
    float*  outf   = (float*)d_out;                    // N*32 fp32

    // ---- contention-free CSR build + transposes ----
    hist_kernel<<<FBLK, 256, 0, stream>>>(dst, H);
    colscan_kernel<<<(NBK + 255) / 256, 256, 0, stream>>>(H, btot);
    bucketscan_kernel<<<1, 1024, 0, stream>>>(btot, bbase, bptr);
    binfill_kernel<<<FBLK, 256, 0, stream>>>(src, dst, H, bbase, tmp);
    bucketfin_kernel<<<NBK, 256, 0, stream>>>(tmp, bptr, esrc, rowptr, dis, n);
    transpose_all_kernel<<<56, 256, 0, stream>>>(W0, W1, W2, wt0, wt1, wt2);

    // ---- layer 0: 128 -> 64, ReLU ----
    gemm_kernel<128, 64><<<(n + 63) / 64, 256, 0, stream>>>(features, wt0, dis, ys, n);
    gather2h_kernel<true><<<(n + 3) / 4, 256, 0, stream>>>(rowptr, esrc, ys, dis, b0, act, n);

    // ---- layer 1: 64 -> 64, ReLU ----
    gemm_kernel<64, 64><<<(n + 63) / 64, 256, 0, stream>>>(act, wt1, dis, ys, n);
    gather2h_kernel<true><<<(n + 3) / 4, 256, 0, stream>>>(rowptr, esrc, ys, dis, b1, act, n);

    // ---- layer 2: 64 -> 32, no ReLU ----
    gemm_kernel<64, 32><<<(n + 63) / 64, 256, 0, stream>>>(act, wt2, dis, ys, n);
    gather4h_kernel<false><<<(n + 3) / 4, 256, 0, stream>>>(rowptr, esrc, ys, dis, b2, outf, n);
}

// Round 13
// 305.201 us; speedup vs baseline: 1.3128x; 1.1092x over previous
//
#include <hip/hip_runtime.h>
#include <hip/hip_fp16.h>

#define N_NODES 100000
#define N_EDGES 1600000
#define NPB 128                                   // nodes per dst-bucket
#define NBK ((N_NODES + NPB - 1) / NPB)           // 782 buckets
#define FBLK 128                                  // fill blocks
#define EPB ((N_EDGES + FBLK - 1) / FBLK)         // 12500 edges per fill block
#define CAP 4096                                  // LDS capacity per bucket (mean 2046, sigma ~45)

typedef _Float16 h8 __attribute__((ext_vector_type(8)));
typedef float f4v __attribute__((ext_vector_type(4)));

// ---------------- pass 1: per-block bucket histograms (validated r9/r10) ----------------

__global__ void __launch_bounds__(256) hist_kernel(const int* __restrict__ dst, int* __restrict__ H) {
    __shared__ int h[NBK];
    for (int i = threadIdx.x; i < NBK; i += 256) h[i] = 0;
    __syncthreads();
    const int e0 = blockIdx.x * EPB;
    const int e1 = min(e0 + EPB, N_EDGES);
    for (int e = e0 + threadIdx.x; e < e1; e += 256) atomicAdd(&h[dst[e] >> 7], 1);
    __syncthreads();
    for (int i = threadIdx.x; i < NBK; i += 256) H[blockIdx.x * NBK + i] = h[i];
}

// ---------------- pass 2a: per-bucket column scan over the 128 blocks ----------------

__global__ void __launch_bounds__(256) colscan_kernel(int* __restrict__ H, int* __restrict__ btot) {
    const int t = blockIdx.x * 256 + threadIdx.x;
    if (t >= NBK) return;
    int run = 0;
    for (int k = 0; k < FBLK; ++k) {
        int idx = k * NBK + t;
        int h = H[idx];
        H[idx] = run;
        run += h;
    }
    btot[t] = run;
}

// ---------------- pass 2b: scan bucket totals -> bucket bases + bptr ----------------

__global__ void __launch_bounds__(1024) bucketscan_kernel(const int* __restrict__ btot,
                                                          int* __restrict__ bbase, int* __restrict__ bptr) {
    __shared__ int sh[1024];
    const int t = threadIdx.x;
    int v = (t < NBK) ? btot[t] : 0;
    sh[t] = v;
    __syncthreads();
    for (int off = 1; off < 1024; off <<= 1) {
        int u = (t >= off) ? sh[t - off] : 0;
        __syncthreads();
        sh[t] += u;
        __syncthreads();
    }
    if (t < NBK) { int e = sh[t] - v; bbase[t] = e; bptr[t] = e; }
    if (t == 0) bptr[NBK] = N_EDGES;
}

// ---------------- pass 3: bin edges by bucket (LDS cursors) ----------------

__global__ void __launch_bounds__(256) binfill_kernel(const int* __restrict__ src, const int* __restrict__ dst,
                                                      const int* __restrict__ H, const int* __restrict__ bbase,
                                                      int* __restrict__ tmp) {
    __shared__ int cur[NBK];
    const int k = blockIdx.x;
    for (int i = threadIdx.x; i < NBK; i += 256) cur[i] = H[k * NBK + i] + bbase[i];
    __syncthreads();
    const int e0 = k * EPB;
    const int e1 = min(e0 + EPB, N_EDGES);
    for (int e = e0 + threadIdx.x; e < e1; e += 256) {
        int s = src[e];
        int d = dst[e];
        int pos = atomicAdd(&cur[d >> 7], 1);
        tmp[pos] = s | ((d & (NPB - 1)) << 20);
    }
}

// ---------------- pass 4: per-bucket count/scan/rowptr/dis + LDS sort -> esrc ----------------

__global__ void __launch_bounds__(256) bucketfin_kernel(const int* __restrict__ tmp, const int* __restrict__ bptr,
                                                        int* __restrict__ esrc, int* __restrict__ rowptr,
                                                        float* __restrict__ dis, int n) {
    __shared__ int buf[CAP];
    __shared__ int cnt[NPB];
    __shared__ int sc[NPB];
    __shared__ int rp[NPB];
    __shared__ int fillc[NPB];
    const int b = blockIdx.x;
    const int d0 = b * NPB;
    const int nd = min(NPB, n - d0);
    const int base = bptr[b], end = bptr[b + 1];
    const int count = end - base;
    const int tid = threadIdx.x;

    for (int i = tid; i < NPB; i += 256) { cnt[i] = 0; fillc[i] = 0; }
    __syncthreads();
    for (int e = base + tid; e < end; e += 256) atomicAdd(&cnt[tmp[e] >> 20], 1);
    __syncthreads();

    if (tid < NPB) sc[tid] = cnt[tid];
    __syncthreads();
    for (int off = 1; off < NPB; off <<= 1) {
        int v = (tid < NPB && tid >= off) ? sc[tid - off] : 0;
        __syncthreads();
        if (tid < NPB) sc[tid] += v;
        __syncthreads();
    }
    if (tid < NPB) {
        int excl = sc[tid] - cnt[tid];
        rp[tid] = excl;
        if (tid < nd) {
            rowptr[d0 + tid] = base + excl;
            dis[d0 + tid] = rsqrtf((float)cnt[tid] + 1.0f);
        }
    }
    if (b == NBK - 1 && tid == 0) rowptr[n] = N_EDGES;
    __syncthreads();

    if (count <= CAP) {
        for (int t = base + tid; t < end; t += 256) {
            int w = tmp[t];
            int ld = w >> 20;
            int pos = rp[ld] + atomicAdd(&fillc[ld], 1);
            buf[pos] = w & 0xFFFFF;
        }
        __syncthreads();
        for (int t = tid; t < count; t += 256) esrc[base + t] = buf[t];
    } else {
        for (int t = base + tid; t < end; t += 256) {
            int w = tmp[t];
            int ld = w >> 20;
            int pos = rp[ld] + atomicAdd(&fillc[ld], 1);
            esrc[base + pos] = w & 0xFFFFF;
        }
    }
}

// ---------------- weight transposes -> fp16 W^T ----------------

__global__ void transpose_all_kernel(const float* __restrict__ W0, const float* __restrict__ W1,
                                     const float* __restrict__ W2, __half* __restrict__ wt0,
                                     __half* __restrict__ wt1, __half* __restrict__ wt2) {
    int i = blockIdx.x * blockDim.x + threadIdx.x;
    if (i < 8192)       { int k = i / 64, c = i % 64;                 wt0[c * 128 + k] = __float2half(W0[i]); }
    else if (i < 12288) { int j = i - 8192;  int k = j / 64, c = j % 64; wt1[c * 64 + k] = __float2half(W1[j]); }
    else if (i < 14336) { int j = i - 12288; int k = j / 32, c = j % 32; wt2[c * 64 + k] = __float2half(W2[j]); }
}

// ---------------- MFMA GEMM: ys[n,DOUT] = fp16(dis[row] * (x[n,DIN] @ W)) ----------------
// 64 rows/block, 4 waves; wave w owns rows w*16..w*16+15, all DOUT cols (NT=DOUT/16 frags).
// A-frag: A[m=lane&15][k=quad*8+j]; B-frag: B[k=quad*8+j][n=lane&15] (wt16 = W^T fp16);
// C/D: col=lane&15, row=quad*4+reg. Epilogue repacks through LDS for coalesced int4 stores.

template <int DIN, int DOUT>
__global__ void __launch_bounds__(256) gemm_kernel(const float* __restrict__ x,
                                                   const __half* __restrict__ wt16,
                                                   const float* __restrict__ dis,
                                                   __half* __restrict__ ys, int n) {
    constexpr int WS = DIN + 8;          // half-element stride (16B-aligned, 2-way banks = free)
    constexpr int NT = DOUT / 16;
    constexpr int KC = DIN / 32;

    __shared__ _Float16 xls[64 * WS];
    __shared__ _Float16 wls[DOUT * WS];

    const int tid  = threadIdx.x;
    const int row0 = blockIdx.x * 64;

    // stage W (fp16, 16B chunks)
    for (int i = tid; i < DOUT * DIN / 8; i += 256) {
        int c = (i * 8) / DIN, k = (i * 8) % DIN;
        *(int4*)&wls[c * WS + k] = *(const int4*)&wt16[c * DIN + k];
    }
    // stage x (fp32 -> fp16)
    for (int i = tid; i < 64 * DIN / 4; i += 256) {
        int r = (i * 4) / DIN, k = (i * 4) % DIN;
        float4 v = make_float4(0.f, 0.f, 0.f, 0.f);
        if (row0 + r < n) v = *(const float4*)&x[(long)(row0 + r) * DIN + k];
        _Float16 h[4] = {(_Float16)v.x, (_Float16)v.y, (_Float16)v.z, (_Float16)v.w};
        *(int2*)&xls[r * WS + k] = *(int2*)h;
    }
    __syncthreads();

    const int wave = tid >> 6;
    const int lane = tid & 63;
    const int m16  = lane & 15;
    const int quad = lane >> 4;

    f4v acc[NT];
#pragma unroll
    for (int t = 0; t < NT; ++t) acc[t] = (f4v){0.f, 0.f, 0.f, 0.f};

    const int arow = wave * 16 + m16;
#pragma unroll
    for (int kc = 0; kc < KC; ++kc) {
        h8 a = *(const h8*)&xls[arow * WS + kc * 32 + quad * 8];
#pragma unroll
        for (int t = 0; t < NT; ++t) {
            h8 b = *(const h8*)&wls[(t * 16 + m16) * WS + kc * 32 + quad * 8];
            acc[t] = __builtin_amdgcn_mfma_f32_16x16x32_f16(a, b, acc[t], 0, 0, 0);
        }
    }

    // epilogue: fold dis, repack via LDS (reuse xls), coalesced int4 stores
    float dsv[4];
    int   lrow[4];
#pragma unroll
    for (int reg = 0; reg < 4; ++reg) {
        lrow[reg] = wave * 16 + quad * 4 + reg;
        int grow  = row0 + lrow[reg];
        dsv[reg]  = (grow < n) ? dis[grow] : 0.f;
    }
    __syncthreads();                      // all LDS fragment reads complete
    _Float16* stage = xls;                // 64*DOUT halves fits in 64*WS
#pragma unroll
    for (int t = 0; t < NT; ++t) {
#pragma unroll
        for (int reg = 0; reg < 4; ++reg)
            stage[lrow[reg] * DOUT + t * 16 + m16] = (_Float16)(acc[t][reg] * dsv[reg]);
    }
    __syncthreads();
    for (int i = tid; i < 64 * DOUT / 8; i += 256) {
        int off = i * 8;
        int r = off / DOUT;
        if (row0 + r < n)
            *(int4*)&ys[(long)row0 * DOUT + off] = *(int4*)&stage[off];
    }
}

// ---------------- gather DOUT=64 (r10-validated shape): 2 nodes/wave, unroll 8 ----------------
// out[d] = dis[d] * (ys[d] + sum_edges ys[s]) + b   (dis_s folded into ys at GEMM)

template <bool RELU>
__global__ void gather2h_kernel(const int* __restrict__ rowptr, const int* __restrict__ esrc,
                                const __half* __restrict__ ys, const float* __restrict__ dis,
                                const float* __restrict__ b, float* __restrict__ out, int n) {
    const int node = blockIdx.x * 8 + (threadIdx.x >> 5);
    const int c = (threadIdx.x & 31) * 2;
    if (node >= n) return;

    float2 yv = __half22float2(*(const __half2*)&ys[(long)node * 64 + c]);
    float ax = yv.x, ay = yv.y;   // self term (ys already dis-scaled)

    int k = rowptr[node];
    const int end = rowptr[node + 1];
    for (; k + 8 <= end; k += 8) {
        int u0 = esrc[k], u1 = esrc[k + 1], u2 = esrc[k + 2], u3 = esrc[k + 3];
        int u4 = esrc[k + 4], u5 = esrc[k + 5], u6 = esrc[k + 6], u7 = esrc[k + 7];
        float2 v0 = __half22float2(*(const __half2*)&ys[(long)u0 * 64 + c]);
        float2 v1 = __half22float2(*(const __half2*)&ys[(long)u1 * 64 + c]);
        float2 v2 = __half22float2(*(const __half2*)&ys[(long)u2 * 64 + c]);
        float2 v3 = __half22float2(*(const __half2*)&ys[(long)u3 * 64 + c]);
        float2 v4 = __half22float2(*(const __half2*)&ys[(long)u4 * 64 + c]);
        float2 v5 = __half22float2(*(const __half2*)&ys[(long)u5 * 64 + c]);
        float2 v6 = __half22float2(*(const __half2*)&ys[(long)u6 * 64 + c]);
        float2 v7 = __half22float2(*(const __half2*)&ys[(long)u7 * 64 + c]);
        ax += v0.x; ay += v0.y;
        ax += v1.x; ay += v1.y;
        ax += v2.x; ay += v2.y;
        ax += v3.x; ay += v3.y;
        ax += v4.x; ay += v4.y;
        ax += v5.x; ay += v5.y;
        ax += v6.x; ay += v6.y;
        ax += v7.x; ay += v7.y;
    }
    for (; k < end; ++k) {
        int u = esrc[k];
        float2 v = __half22float2(*(const __half2*)&ys[(long)u * 64 + c]);
        ax += v.x; ay += v.y;
    }

    const float di = dis[node];
    ax = ax * di + b[c];
    ay = ay * di + b[c + 1];
    if (RELU) { ax = fmaxf(ax, 0.0f); ay = fmaxf(ay, 0.0f); }
    *(float2*)&out[(long)node * 64 + c] = make_float2(ax, ay);
}

// ---------------- gather DOUT=32 (r10-validated shape): 4 nodes/wave, unroll 8 ----------------

template <bool RELU>
__global__ void gather4h_kernel(const int* __restrict__ rowptr, const int* __restrict__ esrc,
                                const __half* __restrict__ ys, const float* __restrict__ dis,
                                const float* __restrict__ b, float* __restrict__ out, int n) {
    const int node = blockIdx.x * 16 + (threadIdx.x >> 4);
    const int c = (threadIdx.x & 15) * 2;
    if (node >= n) return;

    float2 yv = __half22float2(*(const __half2*)&ys[(long)node * 32 + c]);
    float ax = yv.x, ay = yv.y;

    int k = rowptr[node];
    const int end = rowptr[node + 1];
    for (; k + 8 <= end; k += 8) {
        int u0 = esrc[k], u1 = esrc[k + 1], u2 = esrc[k + 2], u3 = esrc[k + 3];
        int u4 = esrc[k + 4], u5 = esrc[k + 5], u6 = esrc[k + 6], u7 = esrc[k + 7];
        float2 v0 = __half22float2(*(const __half2*)&ys[(long)u0 * 32 + c]);
        float2 v1 = __half22float2(*(const __half2*)&ys[(long)u1 * 32 + c]);
        float2 v2 = __half22float2(*(const __half2*)&ys[(long)u2 * 32 + c]);
        float2 v3 = __half22float2(*(const __half2*)&ys[(long)u3 * 32 + c]);
        float2 v4 = __half22float2(*(const __half2*)&ys[(long)u4 * 32 + c]);
        float2 v5 = __half22float2(*(const __half2*)&ys[(long)u5 * 32 + c]);
        float2 v6 = __half22float2(*(const __half2*)&ys[(long)u6 * 32 + c]);
        float2 v7 = __half22float2(*(const __half2*)&ys[(long)u7 * 32 + c]);
        ax += v0.x; ay += v0.y;
        ax += v1.x; ay += v1.y;
        ax += v2.x; ay += v2.y;
        ax += v3.x; ay += v3.y;
        ax += v4.x; ay += v4.y;
        ax += v5.x; ay += v5.y;
        ax += v6.x; ay += v6.y;
        ax += v7.x; ay += v7.y;
    }
    for (; k < end; ++k) {
        int u = esrc[k];
        float2 v = __half22float2(*(const __half2*)&ys[(long)u * 32 + c]);
        ax += v.x; ay += v.y;
    }

    const float di = dis[node];
    ax = ax * di + b[c];
    ay = ay * di + b[c + 1];
    if (RELU) { ax = fmaxf(ax, 0.0f); ay = fmaxf(ay, 0.0f); }
    *(float2*)&out[(long)node * 32 + c] = make_float2(ax, ay);
}

// ---------------- launch ----------------

extern "C" void kernel_launch(void* const* d_in, const int* in_sizes, int n_in,
                              void* d_out, int out_size, void* d_ws, size_t ws_size,
                              hipStream_t stream) {
    const float* features = (const float*)d_in[0];
    const int*   ei       = (const int*)d_in[1];
    const float* W0 = (const float*)d_in[2];
    const float* b0 = (const float*)d_in[3];
    const float* W1 = (const float*)d_in[4];
    const float* b1 = (const float*)d_in[5];
    const float* W2 = (const float*)d_in[6];
    const float* b2 = (const float*)d_in[7];

    const int* src = ei;             // edge_index[0]
    const int* dst = ei + N_EDGES;   // edge_index[1]

    const int n = N_NODES;

    // workspace layout (int slots)
    int*    H      = (int*)d_ws;                       // [0, 131072)
    int*    btot   = (int*)d_ws + 131072;              // [131072, 132096)
    int*    bbase  = (int*)d_ws + 132096;              // [132096, 133120)
    int*    bptr   = (int*)d_ws + 133120;              // [133120, 135168)
    float*  dis    = (float*)d_ws + 135168;            // [135168, 266240)
    int*    rowptr = (int*)d_ws + 266240;              // [266240, 397312)  n+1 fits
    int*    tmp    = (int*)d_ws + 397312;              // E ints
    int*    esrc   = (int*)d_ws + 1997312;             // E ints
    __half* ys     = (__half*)((int*)d_ws + 3597312);  // N*64 halves
    float*  act    = (float*)d_ws + 6797312;           // N*64 floats
    __half* wt0    = (__half*)((int*)d_ws + 13197312); // 8192 halves
    __half* wt1    = (__half*)((int*)d_ws + 13201408); // 4096 halves
    __half* wt2    = (__half*)((int*)d_ws + 13203456); // 2048 halves
    float*  outf   = (float*)d_out;                    // N*32 fp32

    // ---- contention-free CSR build + transposes ----
    hist_kernel<<<FBLK, 256, 0, stream>>>(dst, H);
    colscan_kernel<<<(NBK + 255) / 256, 256, 0, stream>>>(H, btot);
    bucketscan_kernel<<<1, 1024, 0, stream>>>(btot, bbase, bptr);
    binfill_kernel<<<FBLK, 256, 0, stream>>>(src, dst, H, bbase, tmp);
    bucketfin_kernel<<<NBK, 256, 0, stream>>>(tmp, bptr, esrc, rowptr, dis, n);
    transpose_all_kernel<<<56, 256, 0, stream>>>(W0, W1, W2, wt0, wt1, wt2);

    // ---- layer 0: 128 -> 64, ReLU ----
    gemm_kernel<128, 64><<<(n + 63) / 64, 256, 0, stream>>>(features, wt0, dis, ys, n);
    gather2h_kernel<true><<<(n + 7) / 8, 256, 0, stream>>>(rowptr, esrc, ys, dis, b0, act, n);

    // ---- layer 1: 64 -> 64, ReLU ----
    gemm_kernel<64, 64><<<(n + 63) / 64, 256, 0, stream>>>(act, wt1, dis, ys, n);
    gather2h_kernel<true><<<(n + 7) / 8, 256, 0, stream>>>(rowptr, esrc, ys, dis, b1, act, n);

    // ---- layer 2: 64 -> 32, no ReLU ----
    gemm_kernel<64, 32><<<(n + 63) / 64, 256, 0, stream>>>(act, wt2, dis, ys, n);
    gather4h_kernel<false><<<(n + 15) / 16, 256, 0, stream>>>(rowptr, esrc, ys, dis, b2, outf, n);
}